// Round 4
// baseline (172.634 us; speedup 1.0000x reference)
//
#include <hip/hip_runtime.h>

// N=65536 nodes, D=64 feat, K=32 topk, E=N*16 edges (sorted edge_dst).
// Round-4 structure: persistent grid-stride kernels (small grids) — the
// previous 16384-WG-per-kernel shape appeared dispatch-rate-bound (~320
// WG/us explains both build_dense's ~90us floor and aggregate's 51us).
//  - prep_kernel (1024 WGs): fuses CSR indptr boundary-detect + dense-row
//    reconstruction (one wave per node, shfl-broadcast accumulate).
//  - aggregate_kernel (2048 WGs = 8192 waves): grid-stride over nodes;
//    lane = (edge_slot 0..3)*16 + feature_quad; 8 edges / 2x float4 loads
//    in flight per iteration; shfl_xor(16,32) fold; coalesced 256B row I/O.

#define DFEAT 64
#define KTOP  32

__global__ __launch_bounds__(256) void prep_kernel(
    const float* __restrict__ topk_v,
    const int*   __restrict__ topk_i,
    const int*   __restrict__ edge_dst,
    float*       __restrict__ dense,
    int*         __restrict__ indptr,
    int n_nodes, int n_edges)
{
    int tid      = blockIdx.x * blockDim.x + threadIdx.x;
    int nthreads = gridDim.x * blockDim.x;

    // Part 1: indptr[node] = first edge with dst >= node (boundary detect on
    // sorted edge_dst); indptr[n_nodes] = n_edges.
    for (int e = tid; e < n_edges; e += nthreads) {
        int cur  = edge_dst[e];
        int prev = (e == 0) ? -1 : edge_dst[e - 1];
        for (int node = prev + 1; node <= cur; ++node) indptr[node] = e;
        if (e == n_edges - 1) {
            for (int node = cur + 1; node <= n_nodes; ++node) indptr[node] = n_edges;
        }
    }

    // Part 2: dense[node][lane] = sum of topk vals whose idx == lane.
    int lane   = threadIdx.x & 63;
    int wave   = tid >> 6;
    int nwaves = nthreads >> 6;
    for (int node = wave; node < n_nodes; node += nwaves) {
        int   idx = -1;
        float val = 0.0f;
        if (lane < KTOP) {
            idx = topk_i[node * KTOP + lane];
            val = topk_v[node * KTOP + lane];
        }
        float acc = 0.0f;
#pragma unroll
        for (int k = 0; k < KTOP; ++k) {
            int   ik = __shfl(idx, k, 64);
            float vk = __shfl(val, k, 64);
            acc += (ik == lane) ? vk : 0.0f;   // duplicate indices accumulate
        }
        dense[(size_t)node * DFEAT + lane] = acc;
    }
}

__global__ __launch_bounds__(256) void aggregate_kernel(
    const float4* __restrict__ dense4,
    const float4* __restrict__ feat4,
    const float*  __restrict__ eps,
    const int*    __restrict__ edge_src,
    const int*    __restrict__ indptr,
    float4*       __restrict__ out4,
    int n_nodes)
{
    int lane   = threadIdx.x & 63;
    int f      = lane & 15;   // feature quad: floats [4f, 4f+4)
    int eg     = lane >> 4;   // edge slot 0..3
    int wave   = (blockIdx.x * blockDim.x + threadIdx.x) >> 6;
    int nwaves = (gridDim.x * blockDim.x) >> 6;
    float sc   = 1.0f + eps[0];

    for (int node = wave; node < n_nodes; node += nwaves) {
        int start = indptr[node];
        int end   = indptr[node + 1];

        float4 acc = make_float4(0.f, 0.f, 0.f, 0.f);
        for (int base = start; base < end; base += 8) {
            int e0 = base + eg;
            int e1 = base + 4 + eg;
            if (e0 < end) {
                int s0 = edge_src[e0];                    // 16 lanes same addr: broadcast
                float4 r0 = dense4[(size_t)s0 * 16 + f];  // 16 lanes x 16B = 256B row
                acc.x += r0.x; acc.y += r0.y; acc.z += r0.z; acc.w += r0.w;
            }
            if (e1 < end) {
                int s1 = edge_src[e1];
                float4 r1 = dense4[(size_t)s1 * 16 + f];
                acc.x += r1.x; acc.y += r1.y; acc.z += r1.z; acc.w += r1.w;
            }
        }

        // fold the 4 edge slots; lanes with eg==0 end with the full quad sum
        acc.x += __shfl_xor(acc.x, 16, 64);
        acc.y += __shfl_xor(acc.y, 16, 64);
        acc.z += __shfl_xor(acc.z, 16, 64);
        acc.w += __shfl_xor(acc.w, 16, 64);
        acc.x += __shfl_xor(acc.x, 32, 64);
        acc.y += __shfl_xor(acc.y, 32, 64);
        acc.z += __shfl_xor(acc.z, 32, 64);
        acc.w += __shfl_xor(acc.w, 32, 64);

        if (eg == 0) {
            float4 ft = feat4[(size_t)node * 16 + f];
            float4 o;
            o.x = sc * ft.x + acc.x;
            o.y = sc * ft.y + acc.y;
            o.z = sc * ft.z + acc.z;
            o.w = sc * ft.w + acc.w;
            out4[(size_t)node * 16 + f] = o;
        }
    }
}

extern "C" void kernel_launch(void* const* d_in, const int* in_sizes, int n_in,
                              void* d_out, int out_size, void* d_ws, size_t ws_size,
                              hipStream_t stream)
{
    const float* feat     = (const float*)d_in[0];
    const float* topk_v   = (const float*)d_in[1];
    const float* eps      = (const float*)d_in[2];
    const int*   topk_i   = (const int*)d_in[3];
    const int*   edge_src = (const int*)d_in[4];
    const int*   edge_dst = (const int*)d_in[5];
    float*       out      = (float*)d_out;

    int n_nodes = in_sizes[0] / DFEAT;
    int n_edges = in_sizes[4];

    float* dense = (float*)d_ws;                                   // 16 MB
    size_t dense_bytes = (size_t)n_nodes * DFEAT * sizeof(float);
    int*   indptr = (int*)((char*)d_ws + dense_bytes);             // 256 KB

    prep_kernel<<<1024, 256, 0, stream>>>(topk_v, topk_i, edge_dst,
                                          dense, indptr, n_nodes, n_edges);
    aggregate_kernel<<<2048, 256, 0, stream>>>(
        (const float4*)dense, (const float4*)feat, eps, edge_src,
        indptr, (float4*)out, n_nodes);
}

// Round 5
// 168.840 us; speedup vs baseline: 1.0225x; 1.0225x over previous
//
#include <hip/hip_runtime.h>

// N=65536 nodes, D=64 feat, K=32 topk, E=N*16 edges (sorted edge_dst).
// Round-5 structure (post-mortem: shfl chains = ds_bpermute = DS-pipe-bound;
// fixed ~60us harness overhead per call; agg is gather-traffic-bound):
//  1. init:    zero fp32 dense + CSR indptr boundary-detect     (~4 us)
//  2. scatter: one thread per (node,k) pair, global atomicAdd   (~10 us)
//  3. pack:    fp32 dense -> bf16 dense (halves gather traffic) (~4 us)
//  4. agg:     one wave per node, 16 edges/iter in flight, bf16 rows,
//              fp32 accumulate, shfl_xor fold, coalesced out    (~32 us)
// bf16 path gated on ws_size; fp32-agg fallback otherwise.

#define DFEAT 64
#define KTOP  32

__global__ __launch_bounds__(256) void init_kernel(
    const int* __restrict__ edge_dst,
    float4*    __restrict__ dense4,
    int*       __restrict__ indptr,
    int n_nodes, int n_edges)
{
    int tid    = blockIdx.x * blockDim.x + threadIdx.x;
    int stride = gridDim.x * blockDim.x;

    int n_vec4 = n_nodes * (DFEAT / 4);
    float4 z = make_float4(0.f, 0.f, 0.f, 0.f);
    for (int i = tid; i < n_vec4; i += stride) dense4[i] = z;

    for (int e = tid; e < n_edges; e += stride) {
        int cur  = edge_dst[e];
        int prev = (e == 0) ? -1 : edge_dst[e - 1];
        for (int node = prev + 1; node <= cur; ++node) indptr[node] = e;
        if (e == n_edges - 1) {
            for (int node = cur + 1; node <= n_nodes; ++node) indptr[node] = n_edges;
        }
    }
}

__global__ __launch_bounds__(256) void scatter_kernel(
    const float* __restrict__ topk_v,
    const int*   __restrict__ topk_i,
    float*       __restrict__ dense,
    int n_pairs)
{
    int tid    = blockIdx.x * blockDim.x + threadIdx.x;
    int stride = gridDim.x * blockDim.x;
    for (int i = tid; i < n_pairs; i += stride) {
        int   idx = topk_i[i];
        float val = topk_v[i];
        int   node = i >> 5;                       // K == 32
        atomicAdd(&dense[(size_t)node * DFEAT + idx], val);  // dups accumulate
    }
}

__device__ __forceinline__ unsigned short f2bf(float x) {
    unsigned u = __float_as_uint(x);
    u += 0x7fffu + ((u >> 16) & 1u);               // round-to-nearest-even
    return (unsigned short)(u >> 16);
}

__global__ __launch_bounds__(256) void pack_kernel(
    const float2* __restrict__ dense2,
    unsigned int* __restrict__ dense16,
    int n_words)   // n_nodes * 32 words, each = 2 bf16
{
    int tid    = blockIdx.x * blockDim.x + threadIdx.x;
    int stride = gridDim.x * blockDim.x;
    for (int w = tid; w < n_words; w += stride) {
        float2 f = dense2[w];
        dense16[w] = (unsigned int)f2bf(f.x) | ((unsigned int)f2bf(f.y) << 16);
    }
}

__device__ __forceinline__ float bfu(unsigned int u16) {
    return __uint_as_float(u16 << 16);
}

// bf16-row aggregate: lane = edge_slot(0..3)*16 + feature_quad(0..15);
// each iteration gathers 16 edges as 4 independent uint2 row-chunks in flight.
__global__ __launch_bounds__(256) void aggregate_bf16_kernel(
    const uint2*  __restrict__ d16,     // row = 16 x uint2 (64 bf16, 128B)
    const float4* __restrict__ feat4,
    const float*  __restrict__ eps,
    const int*    __restrict__ edge_src,
    const int*    __restrict__ indptr,
    float4*       __restrict__ out4,
    int n_nodes)
{
    int lane   = threadIdx.x & 63;
    int f      = lane & 15;
    int eg     = lane >> 4;
    int wave   = (blockIdx.x * blockDim.x + threadIdx.x) >> 6;
    int nwaves = (gridDim.x * blockDim.x) >> 6;
    float sc   = 1.0f + eps[0];

    for (int node = wave; node < n_nodes; node += nwaves) {
        int start = indptr[node];
        int end   = indptr[node + 1];

        float4 acc = make_float4(0.f, 0.f, 0.f, 0.f);
        for (int base = start; base < end; base += 16) {
#pragma unroll
            for (int u = 0; u < 4; ++u) {
                int e = base + 4 * u + eg;
                if (e < end) {
                    int s = edge_src[e];
                    uint2 r = d16[(size_t)s * 16 + f];   // 8B/lane, 128B/row
                    acc.x += bfu(r.x & 0xffffu);
                    acc.y += bfu(r.x >> 16);
                    acc.z += bfu(r.y & 0xffffu);
                    acc.w += bfu(r.y >> 16);
                }
            }
        }

        acc.x += __shfl_xor(acc.x, 16, 64);
        acc.y += __shfl_xor(acc.y, 16, 64);
        acc.z += __shfl_xor(acc.z, 16, 64);
        acc.w += __shfl_xor(acc.w, 16, 64);
        acc.x += __shfl_xor(acc.x, 32, 64);
        acc.y += __shfl_xor(acc.y, 32, 64);
        acc.z += __shfl_xor(acc.z, 32, 64);
        acc.w += __shfl_xor(acc.w, 32, 64);

        if (eg == 0) {
            float4 ft = feat4[(size_t)node * 16 + f];
            float4 o;
            o.x = sc * ft.x + acc.x;
            o.y = sc * ft.y + acc.y;
            o.z = sc * ft.z + acc.z;
            o.w = sc * ft.w + acc.w;
            out4[(size_t)node * 16 + f] = o;
        }
    }
}

// fp32 fallback (ws too small for packed copy)
__global__ __launch_bounds__(256) void aggregate_f32_kernel(
    const float4* __restrict__ dense4,
    const float4* __restrict__ feat4,
    const float*  __restrict__ eps,
    const int*    __restrict__ edge_src,
    const int*    __restrict__ indptr,
    float4*       __restrict__ out4,
    int n_nodes)
{
    int lane   = threadIdx.x & 63;
    int f      = lane & 15;
    int eg     = lane >> 4;
    int wave   = (blockIdx.x * blockDim.x + threadIdx.x) >> 6;
    int nwaves = (gridDim.x * blockDim.x) >> 6;
    float sc   = 1.0f + eps[0];

    for (int node = wave; node < n_nodes; node += nwaves) {
        int start = indptr[node];
        int end   = indptr[node + 1];

        float4 acc = make_float4(0.f, 0.f, 0.f, 0.f);
        for (int base = start; base < end; base += 16) {
#pragma unroll
            for (int u = 0; u < 4; ++u) {
                int e = base + 4 * u + eg;
                if (e < end) {
                    int s = edge_src[e];
                    float4 r = dense4[(size_t)s * 16 + f];
                    acc.x += r.x; acc.y += r.y; acc.z += r.z; acc.w += r.w;
                }
            }
        }

        acc.x += __shfl_xor(acc.x, 16, 64);
        acc.y += __shfl_xor(acc.y, 16, 64);
        acc.z += __shfl_xor(acc.z, 16, 64);
        acc.w += __shfl_xor(acc.w, 16, 64);
        acc.x += __shfl_xor(acc.x, 32, 64);
        acc.y += __shfl_xor(acc.y, 32, 64);
        acc.z += __shfl_xor(acc.z, 32, 64);
        acc.w += __shfl_xor(acc.w, 32, 64);

        if (eg == 0) {
            float4 ft = feat4[(size_t)node * 16 + f];
            float4 o;
            o.x = sc * ft.x + acc.x;
            o.y = sc * ft.y + acc.y;
            o.z = sc * ft.z + acc.z;
            o.w = sc * ft.w + acc.w;
            out4[(size_t)node * 16 + f] = o;
        }
    }
}

extern "C" void kernel_launch(void* const* d_in, const int* in_sizes, int n_in,
                              void* d_out, int out_size, void* d_ws, size_t ws_size,
                              hipStream_t stream)
{
    const float* feat     = (const float*)d_in[0];
    const float* topk_v   = (const float*)d_in[1];
    const float* eps      = (const float*)d_in[2];
    const int*   topk_i   = (const int*)d_in[3];
    const int*   edge_src = (const int*)d_in[4];
    const int*   edge_dst = (const int*)d_in[5];
    float*       out      = (float*)d_out;

    int n_nodes = in_sizes[0] / DFEAT;
    int n_pairs = in_sizes[1];          // n_nodes * KTOP
    int n_edges = in_sizes[4];

    // ws layout: [dense32: n*64*4] [indptr: (n+1)*4, 256B-aligned] [dense16: n*64*2]
    float* dense32 = (float*)d_ws;
    size_t dense32_bytes = (size_t)n_nodes * DFEAT * sizeof(float);
    size_t indptr_off    = dense32_bytes;
    int*   indptr        = (int*)((char*)d_ws + indptr_off);
    size_t indptr_bytes  = ((size_t)(n_nodes + 1) * sizeof(int) + 255) & ~(size_t)255;
    size_t d16_off       = indptr_off + indptr_bytes;
    size_t d16_bytes     = (size_t)n_nodes * DFEAT * sizeof(unsigned short);
    bool   use_bf16      = (ws_size >= d16_off + d16_bytes);
    unsigned int* dense16 = (unsigned int*)((char*)d_ws + d16_off);

    init_kernel<<<1024, 256, 0, stream>>>(edge_dst, (float4*)dense32, indptr,
                                          n_nodes, n_edges);
    scatter_kernel<<<2048, 256, 0, stream>>>(topk_v, topk_i, dense32, n_pairs);
    if (use_bf16) {
        int n_words = n_nodes * (DFEAT / 2);
        pack_kernel<<<1024, 256, 0, stream>>>((const float2*)dense32, dense16, n_words);
        aggregate_bf16_kernel<<<2048, 256, 0, stream>>>(
            (const uint2*)dense16, (const float4*)feat, eps, edge_src,
            indptr, (float4*)out, n_nodes);
    } else {
        aggregate_f32_kernel<<<2048, 256, 0, stream>>>(
            (const float4*)dense32, (const float4*)feat, eps, edge_src,
            indptr, (float4*)out, n_nodes);
    }
}

// Round 6
// 132.408 us; speedup vs baseline: 1.3038x; 1.2751x over previous
//
#include <hip/hip_runtime.h>

// N=65536 nodes, D=64 feat, K=32 topk, E=N*16 edges (sorted edge_dst).
// Round-6 structure (post-mortem: harness ws-poison fill = fixed ~45us;
// prep chain was ~70us across 3 launches + global atomics; agg is
// gather-latency/L3-bound at ~3.8 TB/s effective):
//  1. prep (2048 WGs, fused): CSR indptr boundary-detect + dense-row build
//     writing bf16 DIRECTLY — per wave 2 nodes in LDS, ds_add_f32 scatter
//     (dup-safe), coalesced 256B packed store. No fp32 dense, no init, no
//     pack kernel, no global atomics.                       (~10 us)
//  2. agg (2048 WGs): 2 independent nodes per wave-iteration (8 gather
//     chains in flight), bf16 rows, fp32 accum, shfl_xor fold. (~35 us)

#define DFEAT 64
#define KTOP  32

__device__ __forceinline__ unsigned short f2bf(float x) {
    unsigned u = __float_as_uint(x);
    u += 0x7fffu + ((u >> 16) & 1u);               // round-to-nearest-even
    return (unsigned short)(u >> 16);
}
__device__ __forceinline__ float bfu(unsigned int u16) {
    return __uint_as_float(u16 << 16);
}

__global__ __launch_bounds__(256) void prep_kernel(
    const float* __restrict__ topk_v,
    const int*   __restrict__ topk_i,
    const int*   __restrict__ edge_dst,
    unsigned int* __restrict__ dense16,   // 32 words (64 bf16) per node
    int*          __restrict__ indptr,
    int n_nodes, int n_edges)
{
    __shared__ float rows[4][2 * DFEAT];  // per wave: 2 node rows
    int tid    = blockIdx.x * blockDim.x + threadIdx.x;
    int stride = gridDim.x * blockDim.x;
    int lane   = threadIdx.x & 63;
    int wid    = threadIdx.x >> 6;
    int wave   = tid >> 6;
    int nwaves = stride >> 6;

    // Part A: indptr[node] = first edge with dst >= node; indptr[n]=E.
    for (int e = tid; e < n_edges; e += stride) {
        int cur  = edge_dst[e];
        int prev = (e == 0) ? -1 : edge_dst[e - 1];
        for (int node = prev + 1; node <= cur; ++node) indptr[node] = e;
        if (e == n_edges - 1) {
            for (int node = cur + 1; node <= n_nodes; ++node) indptr[node] = n_edges;
        }
    }

    // Part B: bf16 dense rows, 2 nodes per wave per trip.
    // lanes 0..31 -> node pair*2 (k=lane), lanes 32..63 -> pair*2+1 (k=lane-32)
    int total_pairs = (n_nodes + 1) / 2;
    int trips = (total_pairs + nwaves - 1) / nwaves;  // uniform across block
    int half = lane >> 5;
    for (int t = 0; t < trips; ++t) {
        int pair   = wave + t * nwaves;
        bool act   = pair < total_pairs;
        int nodeA  = pair * 2;

        rows[wid][lane]         = 0.0f;
        rows[wid][lane + 64]    = 0.0f;
        __syncthreads();

        if (act) {
            size_t base = (size_t)nodeA * KTOP;   // contiguous: A's 32 then B's 32
            int pos = nodeA * 2 + half;           // nodeA or nodeA+1 (as node id check)
            if (nodeA + half < n_nodes) {
                int   idx = topk_i[base + lane];
                float val = topk_v[base + lane];
                atomicAdd(&rows[wid][half * DFEAT + idx], val);  // ds_add_f32
            }
            (void)pos;
        }
        __syncthreads();

        if (act) {
            // pack word `lane` of the 2-row region: floats [2*lane, 2*lane+1]
            int gword = nodeA * 32 + lane;        // global word index
            if (gword < n_nodes * 32) {
                float a = rows[wid][2 * lane];
                float b = rows[wid][2 * lane + 1];
                dense16[gword] = (unsigned int)f2bf(a) | ((unsigned int)f2bf(b) << 16);
            }
        }
        __syncthreads();
    }
}

// Aggregate: lane = edge_slot(0..3)*16 + feature_quad(0..15).
// Two independent nodes per wave-iteration -> 8 row-gathers in flight.
__global__ __launch_bounds__(256) void aggregate_bf16_kernel(
    const uint2*  __restrict__ d16,     // row = 16 x uint2 (64 bf16, 128B)
    const float4* __restrict__ feat4,
    const float*  __restrict__ eps,
    const int*    __restrict__ edge_src,
    const int*    __restrict__ indptr,
    float4*       __restrict__ out4,
    int n_nodes)
{
    int lane   = threadIdx.x & 63;
    int f      = lane & 15;
    int eg     = lane >> 4;
    int wave   = (blockIdx.x * blockDim.x + threadIdx.x) >> 6;
    int nwaves = (gridDim.x * blockDim.x) >> 6;
    float sc   = 1.0f + eps[0];

    for (int nA = wave; nA < n_nodes; nA += 2 * nwaves) {
        int nB = nA + nwaves;
        bool hasB = nB < n_nodes;

        int sA = indptr[nA],  eA = indptr[nA + 1];
        int sB = 0, eB = 0;
        if (hasB) { sB = indptr[nB]; eB = indptr[nB + 1]; }

        // prefetch feat rows (overlaps the gather chain)
        float4 ftA = feat4[(size_t)nA * 16 + f];
        float4 ftB = hasB ? feat4[(size_t)nB * 16 + f] : make_float4(0, 0, 0, 0);

        float4 accA = make_float4(0.f, 0.f, 0.f, 0.f);
        float4 accB = make_float4(0.f, 0.f, 0.f, 0.f);

        int lenA = eA - sA, lenB = eB - sB;
        int lenM = lenA > lenB ? lenA : lenB;
        for (int off = 0; off < lenM; off += 16) {
#pragma unroll
            for (int u = 0; u < 4; ++u) {
                int ea = sA + off + 4 * u + eg;
                int eb = sB + off + 4 * u + eg;
                if (ea < eA) {
                    int s = edge_src[ea];
                    uint2 r = d16[(size_t)s * 16 + f];
                    accA.x += bfu(r.x & 0xffffu);
                    accA.y += bfu(r.x >> 16);
                    accA.z += bfu(r.y & 0xffffu);
                    accA.w += bfu(r.y >> 16);
                }
                if (hasB && eb < eB) {
                    int s = edge_src[eb];
                    uint2 r = d16[(size_t)s * 16 + f];
                    accB.x += bfu(r.x & 0xffffu);
                    accB.y += bfu(r.x >> 16);
                    accB.z += bfu(r.y & 0xffffu);
                    accB.w += bfu(r.y >> 16);
                }
            }
        }

        accA.x += __shfl_xor(accA.x, 16, 64);
        accA.y += __shfl_xor(accA.y, 16, 64);
        accA.z += __shfl_xor(accA.z, 16, 64);
        accA.w += __shfl_xor(accA.w, 16, 64);
        accA.x += __shfl_xor(accA.x, 32, 64);
        accA.y += __shfl_xor(accA.y, 32, 64);
        accA.z += __shfl_xor(accA.z, 32, 64);
        accA.w += __shfl_xor(accA.w, 32, 64);

        accB.x += __shfl_xor(accB.x, 16, 64);
        accB.y += __shfl_xor(accB.y, 16, 64);
        accB.z += __shfl_xor(accB.z, 16, 64);
        accB.w += __shfl_xor(accB.w, 16, 64);
        accB.x += __shfl_xor(accB.x, 32, 64);
        accB.y += __shfl_xor(accB.y, 32, 64);
        accB.z += __shfl_xor(accB.z, 32, 64);
        accB.w += __shfl_xor(accB.w, 32, 64);

        if (eg == 0) {
            float4 o;
            o.x = sc * ftA.x + accA.x;
            o.y = sc * ftA.y + accA.y;
            o.z = sc * ftA.z + accA.z;
            o.w = sc * ftA.w + accA.w;
            out4[(size_t)nA * 16 + f] = o;
            if (hasB) {
                float4 p;
                p.x = sc * ftB.x + accB.x;
                p.y = sc * ftB.y + accB.y;
                p.z = sc * ftB.z + accB.z;
                p.w = sc * ftB.w + accB.w;
                out4[(size_t)nB * 16 + f] = p;
            }
        }
    }
}

extern "C" void kernel_launch(void* const* d_in, const int* in_sizes, int n_in,
                              void* d_out, int out_size, void* d_ws, size_t ws_size,
                              hipStream_t stream)
{
    const float* feat     = (const float*)d_in[0];
    const float* topk_v   = (const float*)d_in[1];
    const float* eps      = (const float*)d_in[2];
    const int*   topk_i   = (const int*)d_in[3];
    const int*   edge_src = (const int*)d_in[4];
    const int*   edge_dst = (const int*)d_in[5];
    float*       out      = (float*)d_out;

    int n_nodes = in_sizes[0] / DFEAT;
    int n_edges = in_sizes[4];

    // ws layout: [dense16: n*64*2 B] [indptr: (n+1)*4 B]
    unsigned int* dense16 = (unsigned int*)d_ws;
    size_t d16_bytes = (size_t)n_nodes * DFEAT * sizeof(unsigned short);
    size_t d16_pad   = (d16_bytes + 255) & ~(size_t)255;
    int*   indptr    = (int*)((char*)d_ws + d16_pad);

    prep_kernel<<<2048, 256, 0, stream>>>(topk_v, topk_i, edge_dst,
                                          dense16, indptr, n_nodes, n_edges);
    aggregate_bf16_kernel<<<2048, 256, 0, stream>>>(
        (const uint2*)dense16, (const float4*)feat, eps, edge_src,
        indptr, (float4*)out, n_nodes);
}

// Round 7
// 126.126 us; speedup vs baseline: 1.3687x; 1.0498x over previous
//
#include <hip/hip_runtime.h>

// N=65536 nodes, D=64 feat, K=32 topk, E=N*16 edges (sorted edge_dst).
// Round-7 (post-mortem R6: agg latency-bound — HBM 21%, VALU 18%; harness
// ws-poison fill ~43us is a fixed floor):
//  1. prep (2048 WGs): indptr boundary-detect + bf16 dense build. LDS rows
//     are wave-private -> NO block barriers (DS ops of a wave are ordered;
//     compiler inserts lgkmcnt waits for the zero->atomic->read chain).
//  2. agg (2048 WGs): uint4 gathers — 8 lanes/row, 8 rows per load instr,
//     2-node interleave -> 32 rows in flight/wave-iter. 3-stage shfl_xor
//     fold; eg0/eg1 lanes jointly store the fp32 out row coalesced.

#define DFEAT 64
#define KTOP  32

__device__ __forceinline__ unsigned short f2bf(float x) {
    unsigned u = __float_as_uint(x);
    u += 0x7fffu + ((u >> 16) & 1u);               // round-to-nearest-even
    return (unsigned short)(u >> 16);
}
__device__ __forceinline__ float bfu(unsigned int u16) {
    return __uint_as_float(u16 << 16);
}

__global__ __launch_bounds__(256) void prep_kernel(
    const float* __restrict__ topk_v,
    const int*   __restrict__ topk_i,
    const int*   __restrict__ edge_dst,
    unsigned int* __restrict__ dense16,   // 32 words (64 bf16) per node
    int*          __restrict__ indptr,
    int n_nodes, int n_edges)
{
    __shared__ float rows[4][2 * DFEAT];  // wave-private 2-node rows
    int tid    = blockIdx.x * blockDim.x + threadIdx.x;
    int stride = gridDim.x * blockDim.x;
    int lane   = threadIdx.x & 63;
    int wid    = threadIdx.x >> 6;
    int wave   = tid >> 6;
    int nwaves = stride >> 6;
    int half   = lane >> 5;

    // Part A: indptr[node] = first edge with dst >= node; indptr[n]=E.
    for (int e = tid; e < n_edges; e += stride) {
        int cur  = edge_dst[e];
        int prev = (e == 0) ? -1 : edge_dst[e - 1];
        for (int node = prev + 1; node <= cur; ++node) indptr[node] = e;
        if (e == n_edges - 1) {
            for (int node = cur + 1; node <= n_nodes; ++node) indptr[node] = n_edges;
        }
    }

    // Part B: bf16 dense rows, 2 nodes per wave trip, no block barriers.
    // lanes 0..31 -> node pair*2, lanes 32..63 -> pair*2+1 (contiguous topk).
    int total_pairs = n_nodes >> 1;
    for (int pair = wave; pair < total_pairs; pair += nwaves) {
        int nodeA = pair * 2;

        rows[wid][lane]      = 0.0f;
        rows[wid][lane + 64] = 0.0f;

        size_t base = (size_t)nodeA * KTOP;       // A's 32 pairs then B's 32
        int   idx = topk_i[base + lane];
        float val = topk_v[base + lane];
        atomicAdd(&rows[wid][half * DFEAT + idx], val);   // ds_add, dup-safe

        float a = rows[wid][2 * lane];
        float b = rows[wid][2 * lane + 1];
        dense16[nodeA * 32 + lane] =
            (unsigned int)f2bf(a) | ((unsigned int)f2bf(b) << 16);
    }
}

// Aggregate: lane = edge_slot eg(0..7)*8 + feature_octet f(0..7).
// Row = 8 x uint4 (64 bf16, 128B); one load instr covers 8 distinct rows.
__global__ __launch_bounds__(256) void aggregate_bf16_kernel(
    const uint4*  __restrict__ d16q,
    const float4* __restrict__ feat4,
    const float*  __restrict__ eps,
    const int*    __restrict__ edge_src,
    const int*    __restrict__ indptr,
    float4*       __restrict__ out4,
    int n_nodes)
{
    int lane   = threadIdx.x & 63;
    int f      = lane & 7;    // feature octet: bf16 [8f, 8f+8)
    int eg     = lane >> 3;   // edge slot 0..7
    int wave   = (blockIdx.x * blockDim.x + threadIdx.x) >> 6;
    int nwaves = (gridDim.x * blockDim.x) >> 6;
    float sc   = 1.0f + eps[0];

    for (int nA = wave; nA < n_nodes; nA += 2 * nwaves) {
        int nB = nA + nwaves;
        bool hasB = nB < n_nodes;

        int sA = indptr[nA],  eA = indptr[nA + 1];
        int sB = 0, eB = 0;
        if (hasB) { sB = indptr[nB]; eB = indptr[nB + 1]; }

        // feat prefetch: eg0 lanes need quad 2f, eg1 lanes quad 2f+1
        float4 ftA = make_float4(0, 0, 0, 0), ftB = make_float4(0, 0, 0, 0);
        if (eg < 2) {
            ftA = feat4[(size_t)nA * 16 + 2 * f + eg];
            if (hasB) ftB = feat4[(size_t)nB * 16 + 2 * f + eg];
        }

        float accA[8] = {0, 0, 0, 0, 0, 0, 0, 0};
        float accB[8] = {0, 0, 0, 0, 0, 0, 0, 0};

        int lenA = eA - sA, lenB = eB - sB;
        int lenM = lenA > lenB ? lenA : lenB;
        for (int off = 0; off < lenM; off += 16) {
#pragma unroll
            for (int u = 0; u < 2; ++u) {
                int ea = sA + off + 8 * u + eg;
                int eb = sB + off + 8 * u + eg;
                if (ea < eA) {
                    int s = edge_src[ea];               // 8 lanes broadcast
                    uint4 r = d16q[(size_t)s * 8 + f];  // 8 rows per instr
                    accA[0] += bfu(r.x & 0xffffu); accA[1] += bfu(r.x >> 16);
                    accA[2] += bfu(r.y & 0xffffu); accA[3] += bfu(r.y >> 16);
                    accA[4] += bfu(r.z & 0xffffu); accA[5] += bfu(r.z >> 16);
                    accA[6] += bfu(r.w & 0xffffu); accA[7] += bfu(r.w >> 16);
                }
                if (hasB && eb < eB) {
                    int s = edge_src[eb];
                    uint4 r = d16q[(size_t)s * 8 + f];
                    accB[0] += bfu(r.x & 0xffffu); accB[1] += bfu(r.x >> 16);
                    accB[2] += bfu(r.y & 0xffffu); accB[3] += bfu(r.y >> 16);
                    accB[4] += bfu(r.z & 0xffffu); accB[5] += bfu(r.z >> 16);
                    accB[6] += bfu(r.w & 0xffffu); accB[7] += bfu(r.w >> 16);
                }
            }
        }

        // fold the 8 edge slots (xor 8,16,32): all lanes get full octet sums
#pragma unroll
        for (int d = 8; d < 64; d <<= 1) {
#pragma unroll
            for (int j = 0; j < 8; ++j) {
                accA[j] += __shfl_xor(accA[j], d, 64);
                accB[j] += __shfl_xor(accB[j], d, 64);
            }
        }

        // store: eg0 lane stores quad 2f (acc[0..3]), eg1 stores 2f+1 (acc[4..7])
        if (eg < 2) {
            int q = eg * 4;
            float4 o;
            o.x = sc * ftA.x + accA[q + 0];
            o.y = sc * ftA.y + accA[q + 1];
            o.z = sc * ftA.z + accA[q + 2];
            o.w = sc * ftA.w + accA[q + 3];
            out4[(size_t)nA * 16 + 2 * f + eg] = o;
            if (hasB) {
                float4 p;
                p.x = sc * ftB.x + accB[q + 0];
                p.y = sc * ftB.y + accB[q + 1];
                p.z = sc * ftB.z + accB[q + 2];
                p.w = sc * ftB.w + accB[q + 3];
                out4[(size_t)nB * 16 + 2 * f + eg] = p;
            }
        }
    }
}

extern "C" void kernel_launch(void* const* d_in, const int* in_sizes, int n_in,
                              void* d_out, int out_size, void* d_ws, size_t ws_size,
                              hipStream_t stream)
{
    const float* feat     = (const float*)d_in[0];
    const float* topk_v   = (const float*)d_in[1];
    const float* eps      = (const float*)d_in[2];
    const int*   topk_i   = (const int*)d_in[3];
    const int*   edge_src = (const int*)d_in[4];
    const int*   edge_dst = (const int*)d_in[5];
    float*       out      = (float*)d_out;

    int n_nodes = in_sizes[0] / DFEAT;
    int n_edges = in_sizes[4];

    // ws layout: [dense16: n*64*2 B] [indptr: (n+1)*4 B]
    unsigned int* dense16 = (unsigned int*)d_ws;
    size_t d16_bytes = (size_t)n_nodes * DFEAT * sizeof(unsigned short);
    size_t d16_pad   = (d16_bytes + 255) & ~(size_t)255;
    int*   indptr    = (int*)((char*)d_ws + d16_pad);

    prep_kernel<<<2048, 256, 0, stream>>>(topk_v, topk_i, edge_dst,
                                          dense16, indptr, n_nodes, n_edges);
    aggregate_bf16_kernel<<<2048, 256, 0, stream>>>(
        (const uint4*)dense16, (const float4*)feat, eps, edge_src,
        indptr, (float4*)out, n_nodes);
}

// Round 8
// 124.543 us; speedup vs baseline: 1.3861x; 1.0127x over previous
//
#include <hip/hip_runtime.h>

// N=65536 nodes, D=64 feat, K=32 topk, E=N*16 edges (sorted edge_dst).
// Round-8 (post-mortem R7: agg < 43us, top-5 all harness ws-poison fill;
// remaining controllable time = agg ~35 + prep ~10):
//  agg restructure: lane = slot(0..7)*8 + feat_octet(0..7); ONE NODE PER
//  SLOT (8192 waves x 8 = 65536 nodes, single pass). A slot's 8 lanes own
//  the full 64-feature row, so accumulation completes in-register:
//  NO shfl fold, no DS ops, direct 2x float4 store. 4-edge unroll gives 4
//  independent src->row gather chains (4KB/wave in flight). Consecutive
//  nodes per wave keep edge_src/indptr loads coalesced.
//  prep unchanged from R7 (barrier-free wave-private LDS build, ~10us).

#define DFEAT 64
#define KTOP  32

__device__ __forceinline__ unsigned short f2bf(float x) {
    unsigned u = __float_as_uint(x);
    u += 0x7fffu + ((u >> 16) & 1u);               // round-to-nearest-even
    return (unsigned short)(u >> 16);
}
__device__ __forceinline__ float bfu(unsigned int u16) {
    return __uint_as_float(u16 << 16);
}

__global__ __launch_bounds__(256) void prep_kernel(
    const float* __restrict__ topk_v,
    const int*   __restrict__ topk_i,
    const int*   __restrict__ edge_dst,
    unsigned int* __restrict__ dense16,   // 32 words (64 bf16) per node
    int*          __restrict__ indptr,
    int n_nodes, int n_edges)
{
    __shared__ float rows[4][2 * DFEAT];  // wave-private 2-node rows
    int tid    = blockIdx.x * blockDim.x + threadIdx.x;
    int stride = gridDim.x * blockDim.x;
    int lane   = threadIdx.x & 63;
    int wid    = threadIdx.x >> 6;
    int wave   = tid >> 6;
    int nwaves = stride >> 6;
    int half   = lane >> 5;

    // Part A: indptr[node] = first edge with dst >= node; indptr[n]=E.
    for (int e = tid; e < n_edges; e += stride) {
        int cur  = edge_dst[e];
        int prev = (e == 0) ? -1 : edge_dst[e - 1];
        for (int node = prev + 1; node <= cur; ++node) indptr[node] = e;
        if (e == n_edges - 1) {
            for (int node = cur + 1; node <= n_nodes; ++node) indptr[node] = n_edges;
        }
    }

    // Part B: bf16 dense rows, 2 nodes per wave trip, no block barriers
    // (rows are wave-private; wave DS ops are program-ordered).
    int total_pairs = n_nodes >> 1;
    for (int pair = wave; pair < total_pairs; pair += nwaves) {
        int nodeA = pair * 2;

        rows[wid][lane]      = 0.0f;
        rows[wid][lane + 64] = 0.0f;

        size_t base = (size_t)nodeA * KTOP;       // A's 32 pairs then B's 32
        int   idx = topk_i[base + lane];
        float val = topk_v[base + lane];
        atomicAdd(&rows[wid][half * DFEAT + idx], val);   // ds_add, dup-safe

        float a = rows[wid][2 * lane];
        float b = rows[wid][2 * lane + 1];
        dense16[nodeA * 32 + lane] =
            (unsigned int)f2bf(a) | ((unsigned int)f2bf(b) << 16);
    }
}

// Aggregate: lane = slot(0..7)*8 + f(0..7); slot s of wave w owns node
// w*8+s. Lane holds bf16 features [8f, 8f+8) of its node's row.
__global__ __launch_bounds__(256) void aggregate_bf16_kernel(
    const uint4*  __restrict__ d16q,    // row = 8 x uint4 (64 bf16, 128B)
    const float4* __restrict__ feat4,
    const float*  __restrict__ eps,
    const int*    __restrict__ edge_src,
    const int*    __restrict__ indptr,
    float4*       __restrict__ out4,
    int n_nodes)
{
    int lane = threadIdx.x & 63;
    int f    = lane & 7;     // feature octet
    int slot = lane >> 3;    // node slot within wave
    int wave = (blockIdx.x * blockDim.x + threadIdx.x) >> 6;
    int node = wave * 8 + slot;
    if (node >= n_nodes) return;          // safe: no shfl/barriers below

    float sc = 1.0f + eps[0];
    int s = indptr[node];
    int e = indptr[node + 1];

    float acc[8] = {0, 0, 0, 0, 0, 0, 0, 0};
    for (int base = s; base < e; base += 4) {
#pragma unroll
        for (int u = 0; u < 4; ++u) {     // 4 independent gather chains
            int ee = base + u;
            if (ee < e) {
                int src = edge_src[ee];               // 8-lane broadcast
                uint4 r = d16q[(size_t)src * 8 + f];  // 8 rows per instr
                acc[0] += bfu(r.x & 0xffffu); acc[1] += bfu(r.x >> 16);
                acc[2] += bfu(r.y & 0xffffu); acc[3] += bfu(r.y >> 16);
                acc[4] += bfu(r.z & 0xffffu); acc[5] += bfu(r.z >> 16);
                acc[6] += bfu(r.w & 0xffffu); acc[7] += bfu(r.w >> 16);
            }
        }
    }

    float4 ft0 = feat4[(size_t)node * 16 + 2 * f];
    float4 ft1 = feat4[(size_t)node * 16 + 2 * f + 1];
    float4 o0, o1;
    o0.x = sc * ft0.x + acc[0];
    o0.y = sc * ft0.y + acc[1];
    o0.z = sc * ft0.z + acc[2];
    o0.w = sc * ft0.w + acc[3];
    o1.x = sc * ft1.x + acc[4];
    o1.y = sc * ft1.y + acc[5];
    o1.z = sc * ft1.z + acc[6];
    o1.w = sc * ft1.w + acc[7];
    out4[(size_t)node * 16 + 2 * f]     = o0;
    out4[(size_t)node * 16 + 2 * f + 1] = o1;
}

extern "C" void kernel_launch(void* const* d_in, const int* in_sizes, int n_in,
                              void* d_out, int out_size, void* d_ws, size_t ws_size,
                              hipStream_t stream)
{
    const float* feat     = (const float*)d_in[0];
    const float* topk_v   = (const float*)d_in[1];
    const float* eps      = (const float*)d_in[2];
    const int*   topk_i   = (const int*)d_in[3];
    const int*   edge_src = (const int*)d_in[4];
    const int*   edge_dst = (const int*)d_in[5];
    float*       out      = (float*)d_out;

    int n_nodes = in_sizes[0] / DFEAT;
    int n_edges = in_sizes[4];

    // ws layout: [dense16: n*64*2 B] [indptr: (n+1)*4 B]
    unsigned int* dense16 = (unsigned int*)d_ws;
    size_t d16_bytes = (size_t)n_nodes * DFEAT * sizeof(unsigned short);
    size_t d16_pad   = (d16_bytes + 255) & ~(size_t)255;
    int*   indptr    = (int*)((char*)d_ws + d16_pad);

    prep_kernel<<<2048, 256, 0, stream>>>(topk_v, topk_i, edge_dst,
                                          dense16, indptr, n_nodes, n_edges);

    int agg_waves  = (n_nodes + 7) / 8;              // one 8-node wave each
    int agg_blocks = (agg_waves * 64 + 255) / 256;   // 4 waves per block
    aggregate_bf16_kernel<<<agg_blocks, 256, 0, stream>>>(
        (const uint4*)dense16, (const float4*)feat, eps, edge_src,
        indptr, (float4*)out, n_nodes);
}